// Round 1
// baseline (234.253 us; speedup 1.0000x reference)
//
#include <hip/hip_runtime.h>

#define EPSF 1e-12f
#define NKNOTS 30
#define NINT 29

// Per-interval cubic-in-t table in LDS: value = a0 + t*(a1 + t*(a2 + t*a3))
// where t = x*29 - idx (uniform linspace(0,1,30) knots).

__device__ __forceinline__ float eval1(float xc, const float4* __restrict__ tab) {
    xc = fminf(fmaxf(xc, 0.0f), 1.0f);
    float s = xc * 29.0f;
    int idx = (int)s;                 // trunc == floor for s >= 0
    idx = idx > (NINT - 1) ? (NINT - 1) : idx;
    float t = s - (float)idx;
    float4 c = tab[idx];
    return fmaf(t, fmaf(t, fmaf(t, c.w, c.z), c.y), c.x);
}

__global__ __launch_bounds__(256) void SimpleSpline_kernel(
    const float* __restrict__ x,
    const float* __restrict__ knots,
    const float* __restrict__ coeffs,
    float* __restrict__ out,
    int n)
{
    __shared__ float4 tab[NINT];
    __shared__ float dsh[NKNOTS];

    const int tid = threadIdx.x;

    // ---- build PCHIP slope d[tid] (lane-parallel, replicates reference math) ----
    if (tid < NKNOTS) {
        float d;
        if (tid == 0) {
            float h0 = knots[1] - knots[0];
            float h1 = knots[2] - knots[1];
            float de0 = (coeffs[1] - coeffs[0]) / (h0 + EPSF);
            float de1 = (coeffs[2] - coeffs[1]) / (h1 + EPSF);
            d = ((2.0f * h0 + h1) * de0 - h0 * de1) / (h0 + h1 + EPSF);
            if (d * de0 <= 0.0f) d = 0.0f;
            if (fabsf(d) > 3.0f * fabsf(de0)) d = 3.0f * de0;
        } else if (tid == NKNOTS - 1) {
            float hN = knots[NKNOTS - 1] - knots[NKNOTS - 2];
            float hM = knots[NKNOTS - 2] - knots[NKNOTS - 3];
            float deN = (coeffs[NKNOTS - 1] - coeffs[NKNOTS - 2]) / (hN + EPSF);
            float deM = (coeffs[NKNOTS - 2] - coeffs[NKNOTS - 3]) / (hM + EPSF);
            d = ((2.0f * hN + hM) * deN - hN * deM) / (hN + hM + EPSF);
            if (d * deN <= 0.0f) d = 0.0f;
            if (fabsf(d) > 3.0f * fabsf(deN)) d = 3.0f * deN;
        } else {
            float hkm1 = knots[tid] - knots[tid - 1];
            float hk   = knots[tid + 1] - knots[tid];
            float dkm1 = (coeffs[tid] - coeffs[tid - 1]) / (hkm1 + EPSF);
            float dk   = (coeffs[tid + 1] - coeffs[tid]) / (hk + EPSF);
            float w1 = 2.0f * hk + hkm1;
            float w2 = hk + 2.0f * hkm1;
            d = 0.0f;
            if (dkm1 * dk > 0.0f)
                d = (w1 + w2) / (w1 / (dkm1 + EPSF) + w2 / (dk + EPSF));
        }
        dsh[tid] = d;
    }
    __syncthreads();

    // ---- per-interval Hermite -> cubic-in-t coefficients ----
    if (tid < NINT) {
        float h = knots[tid + 1] - knots[tid];
        float safe_h = (fabsf(h) < EPSF) ? 1.0f : h;
        float yk  = coeffs[tid];
        float yk1 = coeffs[tid + 1];
        float sdk  = safe_h * dsh[tid];
        float sdk1 = safe_h * dsh[tid + 1];
        tab[tid] = make_float4(yk,
                               sdk,
                               3.0f * (yk1 - yk) - 2.0f * sdk - sdk1,
                               2.0f * (yk - yk1) + sdk + sdk1);
    }
    __syncthreads();

    // ---- streaming elementwise evaluation, float4-vectorized ----
    const int n4 = n >> 2;
    const float4* __restrict__ xv = (const float4*)x;
    float4* __restrict__ ov = (float4*)out;

    const int stride = gridDim.x * blockDim.x;
    for (int i = blockIdx.x * blockDim.x + tid; i < n4; i += stride) {
        float4 v = xv[i];
        float4 r;
        r.x = eval1(v.x, tab);
        r.y = eval1(v.y, tab);
        r.z = eval1(v.z, tab);
        r.w = eval1(v.w, tab);
        ov[i] = r;
    }

    // tail (n % 4 != 0) — first few threads of the grid handle it
    const int rem = n & 3;
    if (rem) {
        const int base = n4 << 2;
        const int gi = blockIdx.x * blockDim.x + tid;
        if (gi < rem) out[base + gi] = eval1(x[base + gi], tab);
    }
}

extern "C" void kernel_launch(void* const* d_in, const int* in_sizes, int n_in,
                              void* d_out, int out_size, void* d_ws, size_t ws_size,
                              hipStream_t stream) {
    const float* x      = (const float*)d_in[0];
    const float* knots  = (const float*)d_in[1];
    const float* coeffs = (const float*)d_in[2];
    float* out = (float*)d_out;
    const int n = in_sizes[0];

    const int block = 256;
    int n4 = n >> 2;
    int blocks = (n4 + block - 1) / block;
    if (blocks > 4096) blocks = 4096;
    if (blocks < 1) blocks = 1;

    SimpleSpline_kernel<<<blocks, block, 0, stream>>>(x, knots, coeffs, out, n);
}